// Round 1
// baseline (375.128 us; speedup 1.0000x reference)
//
#include <hip/hip_runtime.h>
#include <hip/hip_bf16.h>
#include <math.h>

// Problem: batch-hard triplet loss. B=8192, D=128, fp32 inputs, int target.
// dist[i,j] = || emb1[i] - emb2[j] + EPS ||_2 (torch.pairwise_distance semantics)
// loss = mean over rows i with target[i]==1 of
//        max( max_{j:t[j]==1} dist[i,j] - min_{j:t[j]==0} dist[i,j] + MARGIN, 0 )

#define DDIM 128
#define BM 64
#define BN 64
#define LDA 132           // padded leading dim (floats): keeps ds_read_b128 at <=2-way bank alias
#define SPLITS 4          // column-range splits (parallelism across blocks)
#define MARGIN 0.2f
#define EPS 1e-6f

// ---------------- kernel 1: per-row sum and sum-of-squares for both embeddings ----------
__global__ void rowstats_kernel(const float* __restrict__ e1,
                                const float* __restrict__ e2,
                                float* __restrict__ ws, int B) {
    int w    = (blockIdx.x * blockDim.x + threadIdx.x) >> 6;   // global wave id
    int lane = threadIdx.x & 63;
    if (w >= 2 * B) return;
    const float* row;
    float* nrm;
    float* sm;
    int r;
    if (w < B) { r = w;      row = e1 + (size_t)r * DDIM; nrm = ws;          sm = ws + B; }
    else       { r = w - B;  row = e2 + (size_t)r * DDIM; nrm = ws + 2 * B;  sm = ws + 3 * B; }
    float a = row[lane];
    float b = row[lane + 64];
    float s = a + b;
    float n = a * a + b * b;
    #pragma unroll
    for (int off = 32; off > 0; off >>= 1) {
        s += __shfl_down(s, off, 64);
        n += __shfl_down(n, off, 64);
    }
    if (lane == 0) { nrm[r] = n; sm[r] = s; }
}

// ---------------- kernel 2: fused tiled "GEMM" + masked row max/min -------------------
// grid: (B/BM, SPLITS), block: 256 (16x16 threads, 4x4 micro-tile each)
__global__ __launch_bounds__(256, 2)
void tile_kernel(const float* __restrict__ e1, const float* __restrict__ e2,
                 const int* __restrict__ target,
                 const float* __restrict__ ws,          // n1|s1|n2|s2
                 float* __restrict__ posmax_part,       // [SPLITS][B]
                 float* __restrict__ negmin_part,       // [SPLITS][B]
                 int B) {
    __shared__ float As[BM][LDA];
    __shared__ float Bs[BN][LDA];

    const float* n1 = ws;
    const float* s1 = ws + B;
    const float* n2 = ws + 2 * B;
    const float* s2 = ws + 3 * B;

    const int tid = threadIdx.x;
    const int tx  = tid & 15;         // 0..15 -> columns
    const int ty  = tid >> 4;         // 0..15 -> rows
    const int row0    = blockIdx.x * BM;
    const int colSpan = B / SPLITS;
    const int colBeg  = blockIdx.y * colSpan;
    const int colEnd  = colBeg + colSpan;

    // stage A tile once: 64 rows x 128 k  (coalesced float4 loads)
    #pragma unroll
    for (int it = 0; it < 8; ++it) {
        int l  = it * 256 + tid;      // 0..2047
        int r  = l >> 5;              // 32 float4 per row
        int kv = l & 31;
        float4 v = *(const float4*)(e1 + (size_t)(row0 + r) * DDIM + kv * 4);
        *(float4*)(&As[r][kv * 4]) = v;
    }

    // per-thread row constants
    float rn1[4], rs1[4];
    #pragma unroll
    for (int i = 0; i < 4; ++i) {
        int gr = row0 + ty * 4 + i;
        rn1[i] = n1[gr];
        rs1[i] = s1[gr];
    }

    float posmax[4], negmin[4];
    #pragma unroll
    for (int i = 0; i < 4; ++i) { posmax[i] = -INFINITY; negmin[i] = INFINITY; }

    for (int j0 = colBeg; j0 < colEnd; j0 += BN) {
        __syncthreads();   // protect Bs from previous iteration's readers
        #pragma unroll
        for (int it = 0; it < 8; ++it) {
            int l  = it * 256 + tid;
            int r  = l >> 5;
            int kv = l & 31;
            float4 v = *(const float4*)(e2 + (size_t)(j0 + r) * DDIM + kv * 4);
            *(float4*)(&Bs[r][kv * 4]) = v;
        }
        __syncthreads();

        float acc[4][4];
        #pragma unroll
        for (int i = 0; i < 4; ++i)
            #pragma unroll
            for (int j = 0; j < 4; ++j) acc[i][j] = 0.f;

        #pragma unroll 4
        for (int k = 0; k < DDIM; k += 4) {
            float4 a[4], b[4];
            #pragma unroll
            for (int i = 0; i < 4; ++i) a[i] = *(const float4*)(&As[ty * 4 + i][k]);
            #pragma unroll
            for (int j = 0; j < 4; ++j) b[j] = *(const float4*)(&Bs[j * 16 + tx][k]);
            #pragma unroll
            for (int i = 0; i < 4; ++i)
                #pragma unroll
                for (int j = 0; j < 4; ++j) {
                    acc[i][j] += a[i].x * b[j].x;
                    acc[i][j] += a[i].y * b[j].y;
                    acc[i][j] += a[i].z * b[j].z;
                    acc[i][j] += a[i].w * b[j].w;
                }
        }

        // epilogue: distance + masked max/min update
        #pragma unroll
        for (int j = 0; j < 4; ++j) {
            int col = j0 + j * 16 + tx;
            int tg  = target[col];
            float cn2 = n2[col];
            float cs2 = s2[col];
            #pragma unroll
            for (int i = 0; i < 4; ++i) {
                float sq = rn1[i] + cn2 - 2.f * acc[i][j]
                         + 2.f * EPS * (rs1[i] - cs2) + (float)DDIM * EPS * EPS;
                float d = sqrtf(fmaxf(sq, 0.f));
                if (tg == 1) posmax[i] = fmaxf(posmax[i], d);
                else         negmin[i] = fminf(negmin[i], d);
            }
        }
    }

    // reduce across the 16 tx lanes (contiguous lanes within one wave)
    #pragma unroll
    for (int m = 1; m < 16; m <<= 1) {
        #pragma unroll
        for (int i = 0; i < 4; ++i) {
            posmax[i] = fmaxf(posmax[i], __shfl_xor(posmax[i], m, 64));
            negmin[i] = fminf(negmin[i], __shfl_xor(negmin[i], m, 64));
        }
    }
    if (tx == 0) {
        #pragma unroll
        for (int i = 0; i < 4; ++i) {
            int gr = row0 + ty * 4 + i;
            posmax_part[(size_t)blockIdx.y * B + gr] = posmax[i];
            negmin_part[(size_t)blockIdx.y * B + gr] = negmin[i];
        }
    }
}

// ---------------- kernel 3: combine splits, hinge, anchor-mask, mean ------------------
__global__ void finalize_kernel(const float* __restrict__ posmax_part,
                                const float* __restrict__ negmin_part,
                                const int* __restrict__ target,
                                float* __restrict__ out, int B) {
    int tid = threadIdx.x;   // block of 256
    float sum = 0.f, cnt = 0.f;
    for (int i = tid; i < B; i += 256) {
        float pm = -INFINITY, nm = INFINITY;
        #pragma unroll
        for (int s = 0; s < SPLITS; ++s) {
            pm = fmaxf(pm, posmax_part[(size_t)s * B + i]);
            nm = fminf(nm, negmin_part[(size_t)s * B + i]);
        }
        if (target[i] == 1) {
            sum += fmaxf(pm - nm + MARGIN, 0.f);
            cnt += 1.f;
        }
    }
    #pragma unroll
    for (int off = 32; off > 0; off >>= 1) {
        sum += __shfl_down(sum, off, 64);
        cnt += __shfl_down(cnt, off, 64);
    }
    __shared__ float ls[4], lc[4];
    int wv = tid >> 6, ln = tid & 63;
    if (ln == 0) { ls[wv] = sum; lc[wv] = cnt; }
    __syncthreads();
    if (tid == 0) {
        float s = 0.f, c = 0.f;
        #pragma unroll
        for (int i = 0; i < 4; ++i) { s += ls[i]; c += lc[i]; }
        out[0] = s / c;
    }
}

extern "C" void kernel_launch(void* const* d_in, const int* in_sizes, int n_in,
                              void* d_out, int out_size, void* d_ws, size_t ws_size,
                              hipStream_t stream) {
    const float* e1     = (const float*)d_in[0];
    const float* e2     = (const float*)d_in[1];
    const int*   target = (const int*)d_in[2];
    float* out = (float*)d_out;
    const int B = in_sizes[2];          // 8192

    // workspace layout (floats):
    //   [0,B)    n1   [B,2B)  s1   [2B,3B) n2   [3B,4B) s2
    //   [4B, 4B+SPLITS*B)             posmax_part
    //   [4B+SPLITS*B, 4B+2*SPLITS*B)  negmin_part
    float* ws          = (float*)d_ws;
    float* posmax_part = ws + 4 * (size_t)B;
    float* negmin_part = posmax_part + (size_t)SPLITS * B;

    {   // row stats: one wave per row, 2*B rows total, 4 waves/block
        int waves  = 2 * B;
        int blocks = (waves + 3) / 4;
        rowstats_kernel<<<blocks, 256, 0, stream>>>(e1, e2, ws, B);
    }
    {
        dim3 grid(B / BM, SPLITS);
        tile_kernel<<<grid, 256, 0, stream>>>(e1, e2, target, ws,
                                              posmax_part, negmin_part, B);
    }
    finalize_kernel<<<1, 256, 0, stream>>>(posmax_part, negmin_part, target, out, B);
}

// Round 4
// 111.896 us; speedup vs baseline: 3.3525x; 3.3525x over previous
//
#include <hip/hip_runtime.h>
#include <hip/hip_bf16.h>
#include <math.h>

// Batch-hard triplet loss, B=8192, D=128, fp32 in.
// dist^2[i,j] = rowterm[i] + colterm[j] - 2*dot(e1[i], e2[j])
//   rowterm = |a|^2 + 2*eps*sum(a) + D*eps^2   (exact fp32, prep pass)
//   colterm = |b|^2 - 2*eps*sum(b)
// sqrt & max/min commute -> track max/min of (colterm - 2*dot); dot on bf16
// matrix cores. Target folded into cpos/cneg (finite +-1e30 sentinels).
//
// R4 fix vs R2/R3: the 128x128 tile has TWO waves per 64-row half covering
// complementary column halves; they must COMBINE per-row pm/nm via LDS
// before the global write (R2/R3 raced -> half the columns dropped ->
// deterministic absmax 0.3125).

#define DDIM   128
#define SPLITS 8
#define MARGIN 0.2f
#define EPS    1e-6f
#define SENT   1e30f

typedef unsigned short ushort_t;
typedef __attribute__((ext_vector_type(8))) short short8;
typedef __attribute__((ext_vector_type(8))) unsigned short ushort8;
typedef __attribute__((ext_vector_type(4))) float f32x4;

__device__ __forceinline__ ushort_t f2bf(float f) {   // fp32 -> bf16 RNE
    unsigned int u = __float_as_uint(f);
    u = (u + 0x7FFFu + ((u >> 16) & 1u)) >> 16;
    return (ushort_t)u;
}

// ---- kernel 1: exact fp32 row stats ------------------------------------
__global__ void prep_kernel(const float* __restrict__ e1, const float* __restrict__ e2,
                            const int* __restrict__ target,
                            float* __restrict__ rowterm,
                            float* __restrict__ cpos, float* __restrict__ cneg, int B) {
    int w    = (blockIdx.x * blockDim.x + threadIdx.x) >> 6;
    int lane = threadIdx.x & 63;
    if (w >= 2 * B) return;
    bool first = (w < B);
    int r = first ? w : w - B;
    const float* src = (first ? e1 : e2) + (size_t)r * DDIM;
    float2 v = *(const float2*)(src + lane * 2);
    float s = v.x + v.y;
    float n = v.x * v.x + v.y * v.y;
    #pragma unroll
    for (int off = 32; off > 0; off >>= 1) {
        s += __shfl_down(s, off, 64);
        n += __shfl_down(n, off, 64);
    }
    if (lane == 0) {
        if (first) {
            rowterm[r] = n + 2.f * EPS * s + (float)DDIM * EPS * EPS;
        } else {
            float ct = n - 2.f * EPS * s;
            int tg = target[r];
            cpos[r] = (tg == 1) ? ct : -SENT;
            cneg[r] = (tg == 0) ? ct :  SENT;
        }
    }
}

// stage one 128x128 tile: fp32 global -> bf16 in-register -> LDS
__device__ __forceinline__ void stage_tile(const float* __restrict__ g,
                                           ushort_t* __restrict__ lds, int tid) {
    #pragma unroll
    for (int it = 0; it < 8; ++it) {
        int idx = it * 256 + tid;          // 0..2047
        int r   = idx >> 4;                // row 0..127
        int c8  = idx & 15;                // 8-float chunk 0..15
        const float* src = g + (size_t)r * DDIM + c8 * 8;
        float4 v0 = *(const float4*)src;
        float4 v1 = *(const float4*)(src + 4);
        ushort8 o;
        o[0] = f2bf(v0.x); o[1] = f2bf(v0.y); o[2] = f2bf(v0.z); o[3] = f2bf(v0.w);
        o[4] = f2bf(v1.x); o[5] = f2bf(v1.y); o[6] = f2bf(v1.z); o[7] = f2bf(v1.w);
        *(ushort8*)(lds + r * DDIM + c8 * 8) = o;
    }
}

// ---- kernel 2: MFMA tile + fused masked max/min -------------------------
// grid (B/128, SPLITS), block 256 = 4 waves; 128x128 tile, K=128 in LDS.
__global__ __launch_bounds__(256, 2)
void tile_kernel(const float* __restrict__ e1, const float* __restrict__ e2,
                 const float* __restrict__ cpos, const float* __restrict__ cneg,
                 float* __restrict__ pmp, float* __restrict__ nmp, int B) {
    __shared__ __align__(16) ushort_t As[128 * DDIM];   // 32 KB
    __shared__ __align__(16) ushort_t Bs[128 * DDIM];   // 32 KB

    const int tid = threadIdx.x;
    const int w   = tid >> 6;
    const int l   = tid & 63;
    const int lq  = l >> 4;          // quad 0..3
    const int lm  = l & 15;
    const int row0 = blockIdx.x * 128;
    const int colSpan = B / SPLITS;                  // 1024
    const int col0 = blockIdx.y * colSpan;
    const int nTiles = colSpan / 128;                // 8

    stage_tile(e1 + (size_t)row0 * DDIM, As, tid);   // A staged once

    const int wr = (w >> 1) * 64;    // wave quadrant in tile
    const int wc = (w & 1) * 64;

    float pm[4][4], nm[4][4];        // [i][r]: local row = wr + i*16 + lq*4 + r
    #pragma unroll
    for (int i = 0; i < 4; ++i)
        #pragma unroll
        for (int r = 0; r < 4; ++r) { pm[i][r] = -SENT; nm[i][r] = SENT; }

    const ushort_t* aBase = As + (wr + lm) * DDIM + lq * 8;
    const ushort_t* bBase = Bs + (wc + lm) * DDIM + lq * 8;

    for (int t = 0; t < nTiles; ++t) {
        if (t) __syncthreads();      // previous tile's readers done
        stage_tile(e2 + (size_t)(col0 + t * 128) * DDIM, Bs, tid);
        __syncthreads();             // staging visible to all waves

        f32x4 acc[4][4];
        #pragma unroll
        for (int i = 0; i < 4; ++i)
            #pragma unroll
            for (int j = 0; j < 4; ++j)
                acc[i][j] = (f32x4){0.f, 0.f, 0.f, 0.f};

        #pragma unroll
        for (int kk = 0; kk < DDIM; kk += 32) {
            short8 af[4], bf[4];
            #pragma unroll
            for (int i = 0; i < 4; ++i)
                af[i] = *(const short8*)(aBase + i * 16 * DDIM + kk);
            #pragma unroll
            for (int j = 0; j < 4; ++j)
                bf[j] = *(const short8*)(bBase + j * 16 * DDIM + kk);
            #pragma unroll
            for (int i = 0; i < 4; ++i)
                #pragma unroll
                for (int j = 0; j < 4; ++j)
                    acc[i][j] = __builtin_amdgcn_mfma_f32_16x16x32_bf16(
                                    af[i], bf[j], acc[i][j], 0, 0, 0);
        }

        // branchless epilogue in dist^2 space (no sqrt; rowterm deferred)
        #pragma unroll
        for (int j = 0; j < 4; ++j) {
            int col = col0 + t * 128 + wc + j * 16 + lm;   // C/D: col = lane&15
            float cp = cpos[col];
            float cn = cneg[col];
            #pragma unroll
            for (int i = 0; i < 4; ++i)
                #pragma unroll
                for (int r = 0; r < 4; ++r) {
                    float d = acc[i][j][r];
                    pm[i][r] = fmaxf(pm[i][r], fmaf(-2.f, d, cp));
                    nm[i][r] = fminf(nm[i][r], fmaf(-2.f, d, cn));
                }
        }
    }

    // intra-wave: reduce across the 16 column-lanes (rows fixed per (lq,r))
    #pragma unroll
    for (int m = 1; m < 16; m <<= 1) {
        #pragma unroll
        for (int i = 0; i < 4; ++i)
            #pragma unroll
            for (int r = 0; r < 4; ++r) {
                pm[i][r] = fmaxf(pm[i][r], __shfl_xor(pm[i][r], m, 64));
                nm[i][r] = fminf(nm[i][r], __shfl_xor(nm[i][r], m, 64));
            }
    }

    // cross-wave: waves (2h, 2h+1) share rows [h*64, h*64+64) over
    // complementary column halves -> combine via LDS (reuse As as scratch).
    __syncthreads();                       // all waves done reading As/Bs
    float* smP = (float*)As;               // [128]
    float* smN = smP + 128;                // [128]
    if ((w & 1) == 1 && lm == 0) {
        #pragma unroll
        for (int i = 0; i < 4; ++i)
            #pragma unroll
            for (int r = 0; r < 4; ++r) {
                int lr = wr + i * 16 + lq * 4 + r;
                smP[lr] = pm[i][r];
                smN[lr] = nm[i][r];
            }
    }
    __syncthreads();
    if ((w & 1) == 0 && lm == 0) {
        #pragma unroll
        for (int i = 0; i < 4; ++i)
            #pragma unroll
            for (int r = 0; r < 4; ++r) {
                int lr  = wr + i * 16 + lq * 4 + r;     // C/D: row = quad*4+reg
                int row = row0 + lr;
                pmp[(size_t)blockIdx.y * B + row] = fmaxf(pm[i][r], smP[lr]);
                nmp[(size_t)blockIdx.y * B + row] = fminf(nm[i][r], smN[lr]);
            }
    }
}

// ---- kernel 3: per-row combine + hinge, per-block partial sums ----------
__global__ void reduce_kernel(const float* __restrict__ pmp, const float* __restrict__ nmp,
                              const float* __restrict__ rowterm, const int* __restrict__ target,
                              float* __restrict__ bsum, float* __restrict__ bcnt, int B) {
    const int rowsPer = B / gridDim.x;
    const int base = blockIdx.x * rowsPer;
    float s = 0.f, c = 0.f;
    for (int i = threadIdx.x; i < rowsPer; i += blockDim.x) {
        int row = base + i;
        float pmv = -SENT, nmv = SENT;
        #pragma unroll
        for (int sp = 0; sp < SPLITS; ++sp) {
            pmv = fmaxf(pmv, pmp[(size_t)sp * B + row]);
            nmv = fminf(nmv, nmp[(size_t)sp * B + row]);
        }
        float rt = rowterm[row];
        float dp = sqrtf(fmaxf(rt + pmv, 0.f));
        float dn = sqrtf(fmaxf(rt + nmv, 0.f));
        if (target[row] == 1) {
            s += fmaxf(dp - dn + MARGIN, 0.f);
            c += 1.f;
        }
    }
    #pragma unroll
    for (int off = 32; off > 0; off >>= 1) {
        s += __shfl_down(s, off, 64);
        c += __shfl_down(c, off, 64);
    }
    __shared__ float ls[4], lc[4];
    int wv = threadIdx.x >> 6, ln = threadIdx.x & 63;
    if (ln == 0) { ls[wv] = s; lc[wv] = c; }
    __syncthreads();
    if (threadIdx.x == 0) {
        float ss = 0.f, cc = 0.f;
        #pragma unroll
        for (int i = 0; i < 4; ++i) { ss += ls[i]; cc += lc[i]; }
        bsum[blockIdx.x] = ss;
        bcnt[blockIdx.x] = cc;
    }
}

// ---- kernel 4: final combine (64 partials -> scalar) --------------------
__global__ void final_kernel(const float* __restrict__ bsum, const float* __restrict__ bcnt,
                             float* __restrict__ out, int nb) {
    int lane = threadIdx.x;        // 64 threads
    float s = (lane < nb) ? bsum[lane] : 0.f;
    float c = (lane < nb) ? bcnt[lane] : 0.f;
    #pragma unroll
    for (int off = 32; off > 0; off >>= 1) {
        s += __shfl_down(s, off, 64);
        c += __shfl_down(c, off, 64);
    }
    if (lane == 0) out[0] = s / c;
}

extern "C" void kernel_launch(void* const* d_in, const int* in_sizes, int n_in,
                              void* d_out, int out_size, void* d_ws, size_t ws_size,
                              hipStream_t stream) {
    const float* e1     = (const float*)d_in[0];
    const float* e2     = (const float*)d_in[1];
    const int*   target = (const int*)d_in[2];
    float* out = (float*)d_out;
    const int B = in_sizes[2];                       // 8192

    // ws layout (floats): rowterm | cpos | cneg | pmp | nmp | bsum | bcnt  (~0.6 MB)
    float* p = (float*)d_ws;
    float* rowterm = p;              p += B;
    float* cpos    = p;              p += B;
    float* cneg    = p;              p += B;
    float* pmp     = p;              p += (size_t)SPLITS * B;
    float* nmp     = p;              p += (size_t)SPLITS * B;
    float* bsum    = p;              p += 64;
    float* bcnt    = p;

    {   // prep: one wave per row, 2B rows, 4 waves/block
        int blocks = (2 * B + 3) / 4;
        prep_kernel<<<blocks, 256, 0, stream>>>(e1, e2, target, rowterm, cpos, cneg, B);
    }
    {   // 64 row-blocks x 8 col-splits = 512 blocks = exactly 2/CU (64 KB LDS)
        dim3 grid(B / 128, SPLITS);
        tile_kernel<<<grid, 256, 0, stream>>>(e1, e2, cpos, cneg, pmp, nmp, B);
    }
    reduce_kernel<<<64, 256, 0, stream>>>(pmp, nmp, rowterm, target, bsum, bcnt, B);
    final_kernel<<<1, 64, 0, stream>>>(bsum, bcnt, out, 64);
}

// Round 5
// 99.323 us; speedup vs baseline: 3.7768x; 1.1266x over previous
//
#include <hip/hip_runtime.h>
#include <hip/hip_bf16.h>
#include <math.h>

// Batch-hard triplet loss, B=8192, D=128, fp32 in.
// dist^2[i,j] = rowterm[i] + colterm[j] - 2*dot(e1[i], e2[j])
// sqrt & max/min commute -> track max/min of (colterm - 2*dot); dot on bf16
// matrix cores. Target folded into cpos/cneg (finite +-1e30 sentinels).
//
// R5 vs R4: (1) XOR-swizzled LDS tile layout — chunk c of row r stored at
// position c ^ (r&15). Kills the 16-way ds_read_b128 bank conflict
// (SQ_LDS_BANK_CONFLICT 1.47e7 ~= 24 us of the 50 us kernel). Lane's
// swizzle offset is lane-constant in the K-loop (row&15 == lane&15).
// (2) reduce+final merged into one kernel (3 launches total).

#define DDIM   128
#define SPLITS 8
#define MARGIN 0.2f
#define EPS    1e-6f
#define SENT   1e30f

typedef unsigned short ushort_t;
typedef __attribute__((ext_vector_type(8))) short short8;
typedef __attribute__((ext_vector_type(8))) unsigned short ushort8;
typedef __attribute__((ext_vector_type(4))) float f32x4;

__device__ __forceinline__ ushort_t f2bf(float f) {   // fp32 -> bf16 RNE
    unsigned int u = __float_as_uint(f);
    u = (u + 0x7FFFu + ((u >> 16) & 1u)) >> 16;
    return (ushort_t)u;
}

// ---- kernel 1: exact fp32 row stats ------------------------------------
__global__ void prep_kernel(const float* __restrict__ e1, const float* __restrict__ e2,
                            const int* __restrict__ target,
                            float* __restrict__ rowterm,
                            float* __restrict__ cpos, float* __restrict__ cneg, int B) {
    int w    = (blockIdx.x * blockDim.x + threadIdx.x) >> 6;
    int lane = threadIdx.x & 63;
    if (w >= 2 * B) return;
    bool first = (w < B);
    int r = first ? w : w - B;
    const float* src = (first ? e1 : e2) + (size_t)r * DDIM;
    float2 v = *(const float2*)(src + lane * 2);
    float s = v.x + v.y;
    float n = v.x * v.x + v.y * v.y;
    #pragma unroll
    for (int off = 32; off > 0; off >>= 1) {
        s += __shfl_down(s, off, 64);
        n += __shfl_down(n, off, 64);
    }
    if (lane == 0) {
        if (first) {
            rowterm[r] = n + 2.f * EPS * s + (float)DDIM * EPS * EPS;
        } else {
            float ct = n - 2.f * EPS * s;
            int tg = target[r];
            cpos[r] = (tg == 1) ? ct : -SENT;
            cneg[r] = (tg == 0) ? ct :  SENT;
        }
    }
}

// stage one 128x128 tile: fp32 global -> bf16 in-register -> LDS (swizzled)
__device__ __forceinline__ void stage_tile(const float* __restrict__ g,
                                           ushort_t* __restrict__ lds, int tid) {
    #pragma unroll
    for (int it = 0; it < 8; ++it) {
        int idx = it * 256 + tid;          // 0..2047
        int r   = idx >> 4;                // row 0..127
        int c8  = idx & 15;                // 8-float chunk 0..15
        const float* src = g + (size_t)r * DDIM + c8 * 8;
        float4 v0 = *(const float4*)src;
        float4 v1 = *(const float4*)(src + 4);
        ushort8 o;
        o[0] = f2bf(v0.x); o[1] = f2bf(v0.y); o[2] = f2bf(v0.z); o[3] = f2bf(v0.w);
        o[4] = f2bf(v1.x); o[5] = f2bf(v1.y); o[6] = f2bf(v1.z); o[7] = f2bf(v1.w);
        int pos = c8 ^ (r & 15);           // XOR swizzle
        *(ushort8*)(lds + r * DDIM + pos * 8) = o;
    }
}

// ---- kernel 2: MFMA tile + fused masked max/min -------------------------
// grid (B/128, SPLITS), block 256 = 4 waves; 128x128 tile, K=128 in LDS.
__global__ __launch_bounds__(256, 2)
void tile_kernel(const float* __restrict__ e1, const float* __restrict__ e2,
                 const float* __restrict__ cpos, const float* __restrict__ cneg,
                 float* __restrict__ pmp, float* __restrict__ nmp, int B) {
    __shared__ __align__(16) ushort_t As[128 * DDIM];   // 32 KB
    __shared__ __align__(16) ushort_t Bs[128 * DDIM];   // 32 KB

    const int tid = threadIdx.x;
    const int w   = tid >> 6;
    const int l   = tid & 63;
    const int lq  = l >> 4;          // quad 0..3
    const int lm  = l & 15;
    const int row0 = blockIdx.x * 128;
    const int colSpan = B / SPLITS;                  // 1024
    const int col0 = blockIdx.y * colSpan;
    const int nTiles = colSpan / 128;                // 8

    stage_tile(e1 + (size_t)row0 * DDIM, As, tid);   // A staged once

    const int wr = (w >> 1) * 64;    // wave quadrant in tile
    const int wc = (w & 1) * 64;

    float pm[4][4], nm[4][4];        // [i][r]: local row = wr + i*16 + lq*4 + r
    #pragma unroll
    for (int i = 0; i < 4; ++i)
        #pragma unroll
        for (int r = 0; r < 4; ++r) { pm[i][r] = -SENT; nm[i][r] = SENT; }

    // fragment row for lane: (wr|wc) + lm + i*16  -> row&15 == lm, so the
    // swizzled chunk offset ((lq + kk/8) ^ lm) is lane-constant per kk.
    const ushort_t* aRow = As + (wr + lm) * DDIM;
    const ushort_t* bRow = Bs + (wc + lm) * DDIM;

    for (int t = 0; t < nTiles; ++t) {
        if (t) __syncthreads();      // previous tile's readers done
        stage_tile(e2 + (size_t)(col0 + t * 128) * DDIM, Bs, tid);
        __syncthreads();             // staging visible to all waves

        f32x4 acc[4][4];
        #pragma unroll
        for (int i = 0; i < 4; ++i)
            #pragma unroll
            for (int j = 0; j < 4; ++j)
                acc[i][j] = (f32x4){0.f, 0.f, 0.f, 0.f};

        #pragma unroll
        for (int kk = 0; kk < DDIM; kk += 32) {
            const int co = (((lq + (kk >> 3)) ^ lm) << 3);   // swizzled ushort offset
            short8 af[4], bf[4];
            #pragma unroll
            for (int i = 0; i < 4; ++i)
                af[i] = *(const short8*)(aRow + i * 16 * DDIM + co);
            #pragma unroll
            for (int j = 0; j < 4; ++j)
                bf[j] = *(const short8*)(bRow + j * 16 * DDIM + co);
            #pragma unroll
            for (int i = 0; i < 4; ++i)
                #pragma unroll
                for (int j = 0; j < 4; ++j)
                    acc[i][j] = __builtin_amdgcn_mfma_f32_16x16x32_bf16(
                                    af[i], bf[j], acc[i][j], 0, 0, 0);
        }

        // branchless epilogue in dist^2 space (no sqrt; rowterm deferred)
        #pragma unroll
        for (int j = 0; j < 4; ++j) {
            int col = col0 + t * 128 + wc + j * 16 + lm;   // C/D: col = lane&15
            float cp = cpos[col];
            float cn = cneg[col];
            #pragma unroll
            for (int i = 0; i < 4; ++i)
                #pragma unroll
                for (int r = 0; r < 4; ++r) {
                    float d = acc[i][j][r];
                    pm[i][r] = fmaxf(pm[i][r], fmaf(-2.f, d, cp));
                    nm[i][r] = fminf(nm[i][r], fmaf(-2.f, d, cn));
                }
        }
    }

    // intra-wave: reduce across the 16 column-lanes (rows fixed per (lq,r))
    #pragma unroll
    for (int m = 1; m < 16; m <<= 1) {
        #pragma unroll
        for (int i = 0; i < 4; ++i)
            #pragma unroll
            for (int r = 0; r < 4; ++r) {
                pm[i][r] = fmaxf(pm[i][r], __shfl_xor(pm[i][r], m, 64));
                nm[i][r] = fminf(nm[i][r], __shfl_xor(nm[i][r], m, 64));
            }
    }

    // cross-wave: waves (2h, 2h+1) share rows [h*64, h*64+64) over
    // complementary column halves -> combine via LDS (reuse As as scratch).
    __syncthreads();                       // all waves done reading As/Bs
    float* smP = (float*)As;               // [128]
    float* smN = smP + 128;                // [128]
    if ((w & 1) == 1 && lm == 0) {
        #pragma unroll
        for (int i = 0; i < 4; ++i)
            #pragma unroll
            for (int r = 0; r < 4; ++r) {
                int lr = wr + i * 16 + lq * 4 + r;
                smP[lr] = pm[i][r];
                smN[lr] = nm[i][r];
            }
    }
    __syncthreads();
    if ((w & 1) == 0 && lm == 0) {
        #pragma unroll
        for (int i = 0; i < 4; ++i)
            #pragma unroll
            for (int r = 0; r < 4; ++r) {
                int lr  = wr + i * 16 + lq * 4 + r;     // C/D: row = quad*4+reg
                int row = row0 + lr;
                pmp[(size_t)blockIdx.y * B + row] = fmaxf(pm[i][r], smP[lr]);
                nmp[(size_t)blockIdx.y * B + row] = fminf(nm[i][r], smN[lr]);
            }
    }
}

// ---- kernel 3: per-row combine + hinge + mean (single block) ------------
__global__ void reduce_kernel(const float* __restrict__ pmp, const float* __restrict__ nmp,
                              const float* __restrict__ rowterm, const int* __restrict__ target,
                              float* __restrict__ out, int B) {
    float s = 0.f, c = 0.f;
    for (int row = threadIdx.x; row < B; row += blockDim.x) {
        float pmv = -SENT, nmv = SENT;
        #pragma unroll
        for (int sp = 0; sp < SPLITS; ++sp) {
            pmv = fmaxf(pmv, pmp[(size_t)sp * B + row]);
            nmv = fminf(nmv, nmp[(size_t)sp * B + row]);
        }
        float rt = rowterm[row];
        float dp = sqrtf(fmaxf(rt + pmv, 0.f));
        float dn = sqrtf(fmaxf(rt + nmv, 0.f));
        if (target[row] == 1) {
            s += fmaxf(dp - dn + MARGIN, 0.f);
            c += 1.f;
        }
    }
    #pragma unroll
    for (int off = 32; off > 0; off >>= 1) {
        s += __shfl_down(s, off, 64);
        c += __shfl_down(c, off, 64);
    }
    __shared__ float ls[16], lc[16];
    int wv = threadIdx.x >> 6, ln = threadIdx.x & 63;
    if (ln == 0) { ls[wv] = s; lc[wv] = c; }
    __syncthreads();
    if (threadIdx.x == 0) {
        float ss = 0.f, cc = 0.f;
        int nw = blockDim.x >> 6;
        for (int i = 0; i < nw; ++i) { ss += ls[i]; cc += lc[i]; }
        out[0] = ss / cc;
    }
}

extern "C" void kernel_launch(void* const* d_in, const int* in_sizes, int n_in,
                              void* d_out, int out_size, void* d_ws, size_t ws_size,
                              hipStream_t stream) {
    const float* e1     = (const float*)d_in[0];
    const float* e2     = (const float*)d_in[1];
    const int*   target = (const int*)d_in[2];
    float* out = (float*)d_out;
    const int B = in_sizes[2];                       // 8192

    // ws layout (floats): rowterm | cpos | cneg | pmp | nmp   (~0.6 MB)
    float* p = (float*)d_ws;
    float* rowterm = p;              p += B;
    float* cpos    = p;              p += B;
    float* cneg    = p;              p += B;
    float* pmp     = p;              p += (size_t)SPLITS * B;
    float* nmp     = p;

    {   // prep: one wave per row, 2B rows, 4 waves/block
        int blocks = (2 * B + 3) / 4;
        prep_kernel<<<blocks, 256, 0, stream>>>(e1, e2, target, rowterm, cpos, cneg, B);
    }
    {   // 64 row-blocks x 8 col-splits = 512 blocks = exactly 2/CU (64 KB LDS)
        dim3 grid(B / 128, SPLITS);
        tile_kernel<<<grid, 256, 0, stream>>>(e1, e2, cpos, cneg, pmp, nmp, B);
    }
    reduce_kernel<<<1, 1024, 0, stream>>>(pmp, nmp, rowterm, target, out, B);
}

// Round 6
// 94.044 us; speedup vs baseline: 3.9889x; 1.0561x over previous
//
#include <hip/hip_runtime.h>
#include <hip/hip_bf16.h>
#include <math.h>

// Batch-hard triplet loss, B=8192, D=128, fp32 in.
// dist^2[i,j] = rowterm[i] + colterm[j] - 2*dot(e1[i], e2[j])
// sqrt & max/min commute -> track max/min of (colterm - 2*dot); dot on bf16
// matrix cores. Target folded into cpos/cneg (finite +-1e30 sentinels).
//
// R6 vs R5: (1) prep writes persistent bf16 copies (ws is 268 MB; 4 MB used);
// tile stages via global_load_lds width=16 (no VALU convert/pack in hot loop).
// (2) LDS layout: 1 KB DMA chunks (4 rows x 256 B) at pitch 1056 B; the 32 B
// inter-chunk pad makes fragment ds_read_b128 banks = 8*(lm>>2)+4*lq mod 32
// -> exactly 8 accesses/bank = wave64 floor, conflict-free, while each DMA
// chunk stays contiguous (global_load_lds needs base + lane*16).
// (3) reduce parallelized: 32 blocks + device atomics, last block divides.

#define DDIM   128
#define SPLITS 8
#define MARGIN 0.2f
#define EPS    1e-6f
#define SENT   1e30f

#define CHUNK_PITCH 1056           // 1024 B data + 32 B pad
#define WAVE_SPAN   (8 * CHUNK_PITCH)     // 8 chunks (32 rows) per wave
#define TILE_BYTES  (4 * WAVE_SPAN)       // 33792 B per 128x128 bf16 tile

typedef unsigned short ushort_t;
typedef __attribute__((ext_vector_type(8))) short short8;
typedef __attribute__((ext_vector_type(4))) float f32x4;

__device__ __forceinline__ ushort_t f2bf(float f) {   // fp32 -> bf16 RNE
    unsigned int u = __float_as_uint(f);
    u = (u + 0x7FFFu + ((u >> 16) & 1u)) >> 16;
    return (ushort_t)u;
}

__device__ __forceinline__ void g2lds16(const ushort_t* g, void* lds) {
    // wave-uniform lds base; lane i's 16 B land at lds + i*16
    __builtin_amdgcn_global_load_lds(
        (const __attribute__((address_space(1))) unsigned int*)g,
        (__attribute__((address_space(3))) unsigned int*)lds,
        16, 0, 0);
}

// ---- kernel 1: bf16 convert + exact fp32 row stats + zero accumulators ----
__global__ void prep_kernel(const float* __restrict__ e1, const float* __restrict__ e2,
                            const int* __restrict__ target,
                            ushort_t* __restrict__ e1b, ushort_t* __restrict__ e2b,
                            float* __restrict__ rowterm,
                            float* __restrict__ cpos, float* __restrict__ cneg,
                            float* __restrict__ redsum, int* __restrict__ ticket, int B) {
    if (blockIdx.x == 0 && threadIdx.x == 0) {
        redsum[0] = 0.f; redsum[1] = 0.f; *ticket = 0;
    }
    int w    = (blockIdx.x * blockDim.x + threadIdx.x) >> 6;
    int lane = threadIdx.x & 63;
    if (w >= 2 * B) return;
    bool first = (w < B);
    int r = first ? w : w - B;
    const float* src = (first ? e1 : e2) + (size_t)r * DDIM;
    float2 v = *(const float2*)(src + lane * 2);
    ushort_t* dst = (first ? e1b : e2b) + (size_t)r * DDIM;
    ushort2 o; o.x = f2bf(v.x); o.y = f2bf(v.y);
    *(ushort2*)(dst + lane * 2) = o;
    float s = v.x + v.y;
    float n = v.x * v.x + v.y * v.y;
    #pragma unroll
    for (int off = 32; off > 0; off >>= 1) {
        s += __shfl_down(s, off, 64);
        n += __shfl_down(n, off, 64);
    }
    if (lane == 0) {
        if (first) {
            rowterm[r] = n + 2.f * EPS * s + (float)DDIM * EPS * EPS;
        } else {
            float ct = n - 2.f * EPS * s;
            int tg = target[r];
            cpos[r] = (tg == 1) ? ct : -SENT;
            cneg[r] = (tg == 0) ? ct :  SENT;
        }
    }
}

// stage a 128x128 bf16 tile via DMA: wave w -> rows [w*32, w*32+32)
__device__ __forceinline__ void stage_tile_dma(const ushort_t* __restrict__ gRow0,
                                               unsigned char* __restrict__ lds,
                                               int w, int l) {
    const ushort_t* g = gRow0 + (size_t)(w * 32) * DDIM + l * 8;
    unsigned char* lp = lds + w * WAVE_SPAN;
    #pragma unroll
    for (int it = 0; it < 8; ++it)
        g2lds16(g + it * 512, lp + it * CHUNK_PITCH);
}

// ---- kernel 2: MFMA tile + fused masked max/min -------------------------
// grid (B/128, SPLITS), block 256 = 4 waves; 128x128 tile, K=128 in LDS.
__global__ __launch_bounds__(256, 2)
void tile_kernel(const ushort_t* __restrict__ e1b, const ushort_t* __restrict__ e2b,
                 const float* __restrict__ cpos, const float* __restrict__ cneg,
                 float* __restrict__ pmp, float* __restrict__ nmp, int B) {
    __shared__ __align__(16) unsigned char As[TILE_BYTES];   // 33792 B
    __shared__ __align__(16) unsigned char Bs[TILE_BYTES];   // 33792 B

    const int tid = threadIdx.x;
    const int w   = tid >> 6;
    const int l   = tid & 63;
    const int lq  = l >> 4;          // quad 0..3
    const int lm  = l & 15;
    const int row0 = blockIdx.x * 128;
    const int colSpan = B / SPLITS;                  // 1024
    const int col0 = blockIdx.y * colSpan;
    const int nTiles = colSpan / 128;                // 8

    stage_tile_dma(e1b + (size_t)row0 * DDIM, As, w, l);   // A staged once

    const int wr = (w >> 1) * 64;    // wave quadrant in tile
    const int wc = (w & 1) * 64;

    float pm[4][4], nm[4][4];        // [i][r]: local row = wr + i*16 + lq*4 + r
    #pragma unroll
    for (int i = 0; i < 4; ++i)
        #pragma unroll
        for (int r = 0; r < 4; ++r) { pm[i][r] = -SENT; nm[i][r] = SENT; }

    // fragment row R = (wr|wc) + i*16 + lm; addr =
    //   (R>>2)*1056 + (R&3)*256 + lq*16 + kk*2
    //   = laneBase + i*4224 + kk*2   (laneBase lane-constant)
    const unsigned char* aLane = As + ((wr >> 2) + (lm >> 2)) * CHUNK_PITCH
                                    + (lm & 3) * 256 + lq * 16;
    const unsigned char* bLane = Bs + ((wc >> 2) + (lm >> 2)) * CHUNK_PITCH
                                    + (lm & 3) * 256 + lq * 16;

    for (int t = 0; t < nTiles; ++t) {
        if (t) __syncthreads();      // previous tile's readers done
        stage_tile_dma(e2b + (size_t)(col0 + t * 128) * DDIM, Bs, w, l);
        __syncthreads();             // barrier drains vmcnt -> staging visible

        f32x4 acc[4][4];
        #pragma unroll
        for (int i = 0; i < 4; ++i)
            #pragma unroll
            for (int j = 0; j < 4; ++j)
                acc[i][j] = (f32x4){0.f, 0.f, 0.f, 0.f};

        #pragma unroll
        for (int kk = 0; kk < DDIM; kk += 32) {
            const int ko = kk * 2;   // byte offset within row
            short8 af[4], bf[4];
            #pragma unroll
            for (int i = 0; i < 4; ++i)
                af[i] = *(const short8*)(aLane + i * (4 * CHUNK_PITCH) + ko);
            #pragma unroll
            for (int j = 0; j < 4; ++j)
                bf[j] = *(const short8*)(bLane + j * (4 * CHUNK_PITCH) + ko);
            #pragma unroll
            for (int i = 0; i < 4; ++i)
                #pragma unroll
                for (int j = 0; j < 4; ++j)
                    acc[i][j] = __builtin_amdgcn_mfma_f32_16x16x32_bf16(
                                    af[i], bf[j], acc[i][j], 0, 0, 0);
        }

        // branchless epilogue in dist^2 space (no sqrt; rowterm deferred)
        #pragma unroll
        for (int j = 0; j < 4; ++j) {
            int col = col0 + t * 128 + wc + j * 16 + lm;   // C/D: col = lane&15
            float cp = cpos[col];
            float cn = cneg[col];
            #pragma unroll
            for (int i = 0; i < 4; ++i)
                #pragma unroll
                for (int r = 0; r < 4; ++r) {
                    float d = acc[i][j][r];
                    pm[i][r] = fmaxf(pm[i][r], fmaf(-2.f, d, cp));
                    nm[i][r] = fminf(nm[i][r], fmaf(-2.f, d, cn));
                }
        }
    }

    // intra-wave: reduce across the 16 column-lanes (rows fixed per (lq,r))
    #pragma unroll
    for (int m = 1; m < 16; m <<= 1) {
        #pragma unroll
        for (int i = 0; i < 4; ++i)
            #pragma unroll
            for (int r = 0; r < 4; ++r) {
                pm[i][r] = fmaxf(pm[i][r], __shfl_xor(pm[i][r], m, 64));
                nm[i][r] = fminf(nm[i][r], __shfl_xor(nm[i][r], m, 64));
            }
    }

    // cross-wave: waves (2h, 2h+1) share rows over complementary column
    // halves -> combine via LDS (reuse As as scratch).
    __syncthreads();                       // all waves done reading As/Bs
    float* smP = (float*)As;               // [128]
    float* smN = smP + 128;                // [128]
    if ((w & 1) == 1 && lm == 0) {
        #pragma unroll
        for (int i = 0; i < 4; ++i)
            #pragma unroll
            for (int r = 0; r < 4; ++r) {
                int lr = wr + i * 16 + lq * 4 + r;
                smP[lr] = pm[i][r];
                smN[lr] = nm[i][r];
            }
    }
    __syncthreads();
    if ((w & 1) == 0 && lm == 0) {
        #pragma unroll
        for (int i = 0; i < 4; ++i)
            #pragma unroll
            for (int r = 0; r < 4; ++r) {
                int lr  = wr + i * 16 + lq * 4 + r;     // C/D: row = quad*4+reg
                int row = row0 + lr;
                pmp[(size_t)blockIdx.y * B + row] = fmaxf(pm[i][r], smP[lr]);
                nmp[(size_t)blockIdx.y * B + row] = fminf(nm[i][r], smN[lr]);
            }
    }
}

// ---- kernel 3: per-row combine + hinge; atomic partials; last block divides ----
__global__ void reduce_kernel(const float* __restrict__ pmp, const float* __restrict__ nmp,
                              const float* __restrict__ rowterm, const int* __restrict__ target,
                              float* __restrict__ redsum, int* __restrict__ ticket,
                              float* __restrict__ out, int B) {
    int row = blockIdx.x * blockDim.x + threadIdx.x;    // 32 x 256 = 8192
    float s = 0.f, c = 0.f;
    {
        float pmv = -SENT, nmv = SENT;
        #pragma unroll
        for (int sp = 0; sp < SPLITS; ++sp) {
            pmv = fmaxf(pmv, pmp[(size_t)sp * B + row]);
            nmv = fminf(nmv, nmp[(size_t)sp * B + row]);
        }
        float rt = rowterm[row];
        float dp = sqrtf(fmaxf(rt + pmv, 0.f));
        float dn = sqrtf(fmaxf(rt + nmv, 0.f));
        if (target[row] == 1) {
            s = fmaxf(dp - dn + MARGIN, 0.f);
            c = 1.f;
        }
    }
    #pragma unroll
    for (int off = 32; off > 0; off >>= 1) {
        s += __shfl_down(s, off, 64);
        c += __shfl_down(c, off, 64);
    }
    __shared__ float ls[4], lc[4];
    int wv = threadIdx.x >> 6, ln = threadIdx.x & 63;
    if (ln == 0) { ls[wv] = s; lc[wv] = c; }
    __syncthreads();
    if (threadIdx.x == 0) {
        float ss = ls[0] + ls[1] + ls[2] + ls[3];
        float cc = lc[0] + lc[1] + lc[2] + lc[3];
        atomicAdd(&redsum[0], ss);
        atomicAdd(&redsum[1], cc);
        __threadfence();
        int done = atomicAdd(ticket, 1);
        if (done == (int)gridDim.x - 1) {
            __threadfence();
            float fs = __hip_atomic_load(&redsum[0], __ATOMIC_RELAXED, __HIP_MEMORY_SCOPE_AGENT);
            float fc = __hip_atomic_load(&redsum[1], __ATOMIC_RELAXED, __HIP_MEMORY_SCOPE_AGENT);
            out[0] = fs / fc;
        }
    }
}

extern "C" void kernel_launch(void* const* d_in, const int* in_sizes, int n_in,
                              void* d_out, int out_size, void* d_ws, size_t ws_size,
                              hipStream_t stream) {
    const float* e1     = (const float*)d_in[0];
    const float* e2     = (const float*)d_in[1];
    const int*   target = (const int*)d_in[2];
    float* out = (float*)d_out;
    const int B = in_sizes[2];                       // 8192

    // ws layout: e1b | e2b | rowterm | cpos | cneg | pmp | nmp | redsum | ticket (~4.8 MB)
    char* p = (char*)d_ws;
    ushort_t* e1b  = (ushort_t*)p;   p += (size_t)B * DDIM * 2;   // 2 MB
    ushort_t* e2b  = (ushort_t*)p;   p += (size_t)B * DDIM * 2;   // 2 MB
    float* rowterm = (float*)p;      p += (size_t)B * 4;
    float* cpos    = (float*)p;      p += (size_t)B * 4;
    float* cneg    = (float*)p;      p += (size_t)B * 4;
    float* pmp     = (float*)p;      p += (size_t)SPLITS * B * 4;
    float* nmp     = (float*)p;      p += (size_t)SPLITS * B * 4;
    float* redsum  = (float*)p;      p += 2 * 4;
    int*   ticket  = (int*)p;

    {   // prep: one wave per row, 2B rows, 4 waves/block
        int blocks = (2 * B + 3) / 4;
        prep_kernel<<<blocks, 256, 0, stream>>>(e1, e2, target, e1b, e2b,
                                                rowterm, cpos, cneg, redsum, ticket, B);
    }
    {   // 64 row-blocks x 8 col-splits = 512 blocks = 2/CU (66 KB LDS)
        dim3 grid(B / 128, SPLITS);
        tile_kernel<<<grid, 256, 0, stream>>>(e1b, e2b, cpos, cneg, pmp, nmp, B);
    }
    reduce_kernel<<<32, 256, 0, stream>>>(pmp, nmp, rowterm, target,
                                          redsum, ticket, out, B);
}

// Round 7
// 90.549 us; speedup vs baseline: 4.1428x; 1.0386x over previous
//
#include <hip/hip_runtime.h>
#include <hip/hip_bf16.h>
#include <math.h>

// Batch-hard triplet loss, B=8192, D=128, fp32 in.
// dist^2[i,j] = rowterm[i] + colterm[j] - 2*dot(e1[i], e2[j])
// sqrt & max/min commute -> track max/min of (colterm - 2*dot); dot on bf16
// matrix cores. Target folded into cpos/cneg (finite +-1e30 sentinels).
//
// R7 vs R6: A-tile fragments hoisted into registers (16 x b128 = 64 VGPRs)
// before the B-tile loop. R6 re-read A from LDS every tile: 8 waves x 32 KB
// LDS reads/tile = 262 KB/CU/tile ~ 2-3k cyc on the single LDS pipe vs 2k
// cyc MFMA/SIMD -> LDS-read-bound. Hoist halves LDS traffic -> MFMA-bound.
// Staging stays global_load_lds w=16 into the 1056B-pitch padded layout
// (conflict-free, validated R6: absmax 0, SQ_LDS_BANK_CONFLICT ~0).

#define DDIM   128
#define SPLITS 8
#define MARGIN 0.2f
#define EPS    1e-6f
#define SENT   1e30f

#define CHUNK_PITCH 1056           // 1024 B data + 32 B pad
#define WAVE_SPAN   (8 * CHUNK_PITCH)     // 8 chunks (32 rows) per wave
#define TILE_BYTES  (4 * WAVE_SPAN)       // 33792 B per 128x128 bf16 tile

typedef unsigned short ushort_t;
typedef __attribute__((ext_vector_type(8))) short short8;
typedef __attribute__((ext_vector_type(4))) float f32x4;

__device__ __forceinline__ ushort_t f2bf(float f) {   // fp32 -> bf16 RNE
    unsigned int u = __float_as_uint(f);
    u = (u + 0x7FFFu + ((u >> 16) & 1u)) >> 16;
    return (ushort_t)u;
}

__device__ __forceinline__ void g2lds16(const ushort_t* g, void* lds) {
    // wave-uniform lds base; lane i's 16 B land at lds + i*16
    __builtin_amdgcn_global_load_lds(
        (const __attribute__((address_space(1))) unsigned int*)g,
        (__attribute__((address_space(3))) unsigned int*)lds,
        16, 0, 0);
}

// ---- kernel 1: bf16 convert + exact fp32 row stats + zero accumulators ----
__global__ void prep_kernel(const float* __restrict__ e1, const float* __restrict__ e2,
                            const int* __restrict__ target,
                            ushort_t* __restrict__ e1b, ushort_t* __restrict__ e2b,
                            float* __restrict__ rowterm,
                            float* __restrict__ cpos, float* __restrict__ cneg,
                            float* __restrict__ redsum, int* __restrict__ ticket, int B) {
    if (blockIdx.x == 0 && threadIdx.x == 0) {
        redsum[0] = 0.f; redsum[1] = 0.f; *ticket = 0;
    }
    int w    = (blockIdx.x * blockDim.x + threadIdx.x) >> 6;
    int lane = threadIdx.x & 63;
    if (w >= 2 * B) return;
    bool first = (w < B);
    int r = first ? w : w - B;
    const float* src = (first ? e1 : e2) + (size_t)r * DDIM;
    float2 v = *(const float2*)(src + lane * 2);
    ushort_t* dst = (first ? e1b : e2b) + (size_t)r * DDIM;
    ushort2 o; o.x = f2bf(v.x); o.y = f2bf(v.y);
    *(ushort2*)(dst + lane * 2) = o;
    float s = v.x + v.y;
    float n = v.x * v.x + v.y * v.y;
    #pragma unroll
    for (int off = 32; off > 0; off >>= 1) {
        s += __shfl_down(s, off, 64);
        n += __shfl_down(n, off, 64);
    }
    if (lane == 0) {
        if (first) {
            rowterm[r] = n + 2.f * EPS * s + (float)DDIM * EPS * EPS;
        } else {
            float ct = n - 2.f * EPS * s;
            int tg = target[r];
            cpos[r] = (tg == 1) ? ct : -SENT;
            cneg[r] = (tg == 0) ? ct :  SENT;
        }
    }
}

// stage a 128x128 bf16 tile via DMA: wave w -> rows [w*32, w*32+32)
__device__ __forceinline__ void stage_tile_dma(const ushort_t* __restrict__ gRow0,
                                               unsigned char* __restrict__ lds,
                                               int w, int l) {
    const ushort_t* g = gRow0 + (size_t)(w * 32) * DDIM + l * 8;
    unsigned char* lp = lds + w * WAVE_SPAN;
    #pragma unroll
    for (int it = 0; it < 8; ++it)
        g2lds16(g + it * 512, lp + it * CHUNK_PITCH);
}

// ---- kernel 2: MFMA tile + fused masked max/min -------------------------
// grid (B/128, SPLITS), block 256 = 4 waves; 128x128 tile, K=128 in LDS.
__global__ __launch_bounds__(256, 2)
void tile_kernel(const ushort_t* __restrict__ e1b, const ushort_t* __restrict__ e2b,
                 const float* __restrict__ cpos, const float* __restrict__ cneg,
                 float* __restrict__ pmp, float* __restrict__ nmp, int B) {
    __shared__ __align__(16) unsigned char As[TILE_BYTES];   // 33792 B
    __shared__ __align__(16) unsigned char Bs[TILE_BYTES];   // 33792 B

    const int tid = threadIdx.x;
    const int w   = tid >> 6;
    const int l   = tid & 63;
    const int lq  = l >> 4;          // quad 0..3
    const int lm  = l & 15;
    const int row0 = blockIdx.x * 128;
    const int colSpan = B / SPLITS;                  // 1024
    const int col0 = blockIdx.y * colSpan;
    const int nTiles = colSpan / 128;                // 8

    const int wr = (w >> 1) * 64;    // wave quadrant in tile
    const int wc = (w & 1) * 64;

    // fragment row R = (wr|wc) + i*16 + lm; byte addr =
    //   (R>>2)*1056 + (R&3)*256 + lq*16 + kk*2  (laneBase lane-constant)
    const unsigned char* aLane = As + ((wr >> 2) + (lm >> 2)) * CHUNK_PITCH
                                    + (lm & 3) * 256 + lq * 16;
    const unsigned char* bLane = Bs + ((wc >> 2) + (lm >> 2)) * CHUNK_PITCH
                                    + (lm & 3) * 256 + lq * 16;

    // stage A once + first B tile, then hoist A fragments into registers
    stage_tile_dma(e1b + (size_t)row0 * DDIM, As, w, l);
    stage_tile_dma(e2b + (size_t)col0 * DDIM, Bs, w, l);
    __syncthreads();                 // drains vmcnt -> both tiles visible

    short8 afr[4][4];                // [i][k4]: rows wr+i*16+lm, k = k4*32..
    #pragma unroll
    for (int i = 0; i < 4; ++i)
        #pragma unroll
        for (int k4 = 0; k4 < 4; ++k4)
            afr[i][k4] = *(const short8*)(aLane + i * (4 * CHUNK_PITCH) + k4 * 64);

    float pm[4][4], nm[4][4];        // [i][r]: local row = wr + i*16 + lq*4 + r
    #pragma unroll
    for (int i = 0; i < 4; ++i)
        #pragma unroll
        for (int r = 0; r < 4; ++r) { pm[i][r] = -SENT; nm[i][r] = SENT; }

    for (int t = 0; t < nTiles; ++t) {
        f32x4 acc[4][4];
        #pragma unroll
        for (int i = 0; i < 4; ++i)
            #pragma unroll
            for (int j = 0; j < 4; ++j)
                acc[i][j] = (f32x4){0.f, 0.f, 0.f, 0.f};

        #pragma unroll
        for (int kk = 0; kk < DDIM; kk += 32) {
            const int k4 = kk >> 5;
            const int ko = kk * 2;   // byte offset within row
            short8 bf[4];
            #pragma unroll
            for (int j = 0; j < 4; ++j)
                bf[j] = *(const short8*)(bLane + j * (4 * CHUNK_PITCH) + ko);
            #pragma unroll
            for (int i = 0; i < 4; ++i)
                #pragma unroll
                for (int j = 0; j < 4; ++j)
                    acc[i][j] = __builtin_amdgcn_mfma_f32_16x16x32_bf16(
                                    afr[i][k4], bf[j], acc[i][j], 0, 0, 0);
        }

        // branchless epilogue in dist^2 space (no sqrt; rowterm deferred)
        #pragma unroll
        for (int j = 0; j < 4; ++j) {
            int col = col0 + t * 128 + wc + j * 16 + lm;   // C/D: col = lane&15
            float cp = cpos[col];
            float cn = cneg[col];
            #pragma unroll
            for (int i = 0; i < 4; ++i)
                #pragma unroll
                for (int r = 0; r < 4; ++r) {
                    float d = acc[i][j][r];
                    pm[i][r] = fmaxf(pm[i][r], fmaf(-2.f, d, cp));
                    nm[i][r] = fminf(nm[i][r], fmaf(-2.f, d, cn));
                }
        }

        if (t + 1 < nTiles) {
            __syncthreads();         // all waves done reading Bs
            stage_tile_dma(e2b + (size_t)(col0 + (t + 1) * 128) * DDIM, Bs, w, l);
            __syncthreads();         // staged tile visible
        }
    }

    // intra-wave: reduce across the 16 column-lanes (rows fixed per (lq,r))
    #pragma unroll
    for (int m = 1; m < 16; m <<= 1) {
        #pragma unroll
        for (int i = 0; i < 4; ++i)
            #pragma unroll
            for (int r = 0; r < 4; ++r) {
                pm[i][r] = fmaxf(pm[i][r], __shfl_xor(pm[i][r], m, 64));
                nm[i][r] = fminf(nm[i][r], __shfl_xor(nm[i][r], m, 64));
            }
    }

    // cross-wave: waves (2h, 2h+1) share rows over complementary column
    // halves -> combine via LDS (reuse As as scratch; A lives in registers).
    __syncthreads();
    float* smP = (float*)As;               // [128]
    float* smN = smP + 128;                // [128]
    if ((w & 1) == 1 && lm == 0) {
        #pragma unroll
        for (int i = 0; i < 4; ++i)
            #pragma unroll
            for (int r = 0; r < 4; ++r) {
                int lr = wr + i * 16 + lq * 4 + r;
                smP[lr] = pm[i][r];
                smN[lr] = nm[i][r];
            }
    }
    __syncthreads();
    if ((w & 1) == 0 && lm == 0) {
        #pragma unroll
        for (int i = 0; i < 4; ++i)
            #pragma unroll
            for (int r = 0; r < 4; ++r) {
                int lr  = wr + i * 16 + lq * 4 + r;     // C/D: row = quad*4+reg
                int row = row0 + lr;
                pmp[(size_t)blockIdx.y * B + row] = fmaxf(pm[i][r], smP[lr]);
                nmp[(size_t)blockIdx.y * B + row] = fminf(nm[i][r], smN[lr]);
            }
    }
}

// ---- kernel 3: per-row combine + hinge; atomic partials; last block divides ----
__global__ void reduce_kernel(const float* __restrict__ pmp, const float* __restrict__ nmp,
                              const float* __restrict__ rowterm, const int* __restrict__ target,
                              float* __restrict__ redsum, int* __restrict__ ticket,
                              float* __restrict__ out, int B) {
    int row = blockIdx.x * blockDim.x + threadIdx.x;    // 32 x 256 = 8192
    float s = 0.f, c = 0.f;
    {
        float pmv = -SENT, nmv = SENT;
        #pragma unroll
        for (int sp = 0; sp < SPLITS; ++sp) {
            pmv = fmaxf(pmv, pmp[(size_t)sp * B + row]);
            nmv = fminf(nmv, nmp[(size_t)sp * B + row]);
        }
        float rt = rowterm[row];
        float dp = sqrtf(fmaxf(rt + pmv, 0.f));
        float dn = sqrtf(fmaxf(rt + nmv, 0.f));
        if (target[row] == 1) {
            s = fmaxf(dp - dn + MARGIN, 0.f);
            c = 1.f;
        }
    }
    #pragma unroll
    for (int off = 32; off > 0; off >>= 1) {
        s += __shfl_down(s, off, 64);
        c += __shfl_down(c, off, 64);
    }
    __shared__ float ls[4], lc[4];
    int wv = threadIdx.x >> 6, ln = threadIdx.x & 63;
    if (ln == 0) { ls[wv] = s; lc[wv] = c; }
    __syncthreads();
    if (threadIdx.x == 0) {
        float ss = ls[0] + ls[1] + ls[2] + ls[3];
        float cc = lc[0] + lc[1] + lc[2] + lc[3];
        atomicAdd(&redsum[0], ss);
        atomicAdd(&redsum[1], cc);
        __threadfence();
        int done = atomicAdd(ticket, 1);
        if (done == (int)gridDim.x - 1) {
            __threadfence();
            float fs = __hip_atomic_load(&redsum[0], __ATOMIC_RELAXED, __HIP_MEMORY_SCOPE_AGENT);
            float fc = __hip_atomic_load(&redsum[1], __ATOMIC_RELAXED, __HIP_MEMORY_SCOPE_AGENT);
            out[0] = fs / fc;
        }
    }
}

extern "C" void kernel_launch(void* const* d_in, const int* in_sizes, int n_in,
                              void* d_out, int out_size, void* d_ws, size_t ws_size,
                              hipStream_t stream) {
    const float* e1     = (const float*)d_in[0];
    const float* e2     = (const float*)d_in[1];
    const int*   target = (const int*)d_in[2];
    float* out = (float*)d_out;
    const int B = in_sizes[2];                       // 8192

    // ws layout: e1b | e2b | rowterm | cpos | cneg | pmp | nmp | redsum | ticket (~4.8 MB)
    char* p = (char*)d_ws;
    ushort_t* e1b  = (ushort_t*)p;   p += (size_t)B * DDIM * 2;   // 2 MB
    ushort_t* e2b  = (ushort_t*)p;   p += (size_t)B * DDIM * 2;   // 2 MB
    float* rowterm = (float*)p;      p += (size_t)B * 4;
    float* cpos    = (float*)p;      p += (size_t)B * 4;
    float* cneg    = (float*)p;      p += (size_t)B * 4;
    float* pmp     = (float*)p;      p += (size_t)SPLITS * B * 4;
    float* nmp     = (float*)p;      p += (size_t)SPLITS * B * 4;
    float* redsum  = (float*)p;      p += 2 * 4;
    int*   ticket  = (int*)p;

    {   // prep: one wave per row, 2B rows, 4 waves/block
        int blocks = (2 * B + 3) / 4;
        prep_kernel<<<blocks, 256, 0, stream>>>(e1, e2, target, e1b, e2b,
                                                rowterm, cpos, cneg, redsum, ticket, B);
    }
    {   // 64 row-blocks x 8 col-splits = 512 blocks = 2/CU (66 KB LDS)
        dim3 grid(B / 128, SPLITS);
        tile_kernel<<<grid, 256, 0, stream>>>(e1b, e2b, cpos, cneg, pmp, nmp, B);
    }
    reduce_kernel<<<32, 256, 0, stream>>>(pmp, nmp, rowterm, target,
                                          redsum, ticket, out, B);
}